// Round 1
// baseline (271.733 us; speedup 1.0000x reference)
//
#include <hip/hip_runtime.h>

typedef float        f32x4  __attribute__((ext_vector_type(4)));
typedef __bf16       bf16x8 __attribute__((ext_vector_type(8)));
typedef unsigned int u32x2  __attribute__((ext_vector_type(2)));
typedef unsigned int u32x4  __attribute__((ext_vector_type(4)));
typedef unsigned short u16;

#define MFMA16(a,b,c) __builtin_amdgcn_mfma_f32_16x16x32_bf16((a),(b),(c),0,0,0)

// ---- fp32 -> bf16 hi/lo split (RNE). a ~= hi + lo, |err| ~ 1e-5 rel ----
__device__ __forceinline__ unsigned bf_rnd(float x) {
    unsigned u = __float_as_uint(x);
    return (u + 0x7FFFu + ((u >> 16) & 1u)) & 0xFFFF0000u;
}
__device__ __forceinline__ void split_bf(float x, unsigned &h, unsigned &l) {
    unsigned hr = bf_rnd(x);
    h = hr >> 16;
    float lo = x - __uint_as_float(hr);
    l = bf_rnd(lo) >> 16;
}
__device__ __forceinline__ void split4(const f32x4 v, u32x2 &hp, u32x2 &lp) {
    unsigned h0,l0,h1,l1,h2,l2,h3,l3;
    split_bf(v[0],h0,l0); split_bf(v[1],h1,l1);
    split_bf(v[2],h2,l2); split_bf(v[3],h3,l3);
    hp[0] = h0 | (h1 << 16); hp[1] = h2 | (h3 << 16);
    lp[0] = l0 | (l1 << 16); lp[1] = l2 | (l3 << 16);
}

// LDS tiles are [row][128 k] bf16 = 256 B rows; XOR-swizzle bits 4..6 by row&7
// (G4: spreads the 16-lane same-column ds_read_b128 across all bank groups).
__device__ __forceinline__ bf16x8 ldfrag(const u16* base, int row, int kb) {
    int off = ((row << 8) + kb) ^ ((row & 7) << 4);
    return __builtin_bit_cast(bf16x8, *(const u32x4*)((const char*)base + off));
}
__device__ __forceinline__ void stlds8(u16* base, int row, int colbyte, u32x2 v) {
    int off = ((row << 8) + colbyte) ^ ((row & 7) << 4);
    *(u32x2*)((char*)base + off) = v;
}

// =====================================================================
// K1: fused edge mapper + msg_e partial reduction.
// block = (b, chunk of 8 i).  For each i: Em = relu(E[b,i] @ We + be) via
// 3-pass hi/lo bf16 MFMA on a 128x128 tile, then P[j,f] += A[b,i,j]*Em[j,f]
// in registers.  Partials (one 128x128 tile per block) -> ws.
// =====================================================================
__global__ __launch_bounds__(256, 1) void k_edge(
    const float* __restrict__ E, const float* __restrict__ A,
    const float* __restrict__ We, const float* __restrict__ be,
    float* __restrict__ part)
{
    __shared__ __align__(16) u16 sEhi[128*128];
    __shared__ __align__(16) u16 sElo[128*128];
    __shared__ __align__(16) u16 sWhi[128*128];   // WeT[f][e] hi
    __shared__ __align__(16) u16 sWlo[128*128];   // WeT[f][e] lo
    __shared__ __align__(16) float sA[128];
    __shared__ float sBe[128];

    const int tid  = threadIdx.x;
    const int lane = tid & 63;
    const int wid  = tid >> 6;
    const int wm   = (wid >> 1) << 6;   // wave j-offset: 0/64
    const int wn   = (wid & 1)  << 6;   // wave f-offset: 0/64
    const int b    = blockIdx.x >> 4;
    const int c    = blockIdx.x & 15;
    const int i0   = c << 3;

    // ---- stage WeT (transposed) hi/lo, once per block ----
    {
        const int f  = tid & 127;
        const int eo = tid >> 7;               // 0/1
        #pragma unroll
        for (int q = 0; q < 16; ++q) {
            const int eq = eo + q*2;           // 0..31
            const int e0 = eq << 2;
            f32x4 w;
            w[0] = We[(e0+0)*128 + f];
            w[1] = We[(e0+1)*128 + f];
            w[2] = We[(e0+2)*128 + f];
            w[3] = We[(e0+3)*128 + f];
            u32x2 hp, lp; split4(w, hp, lp);
            stlds8(sWhi, f, e0*2, hp);
            stlds8(sWlo, f, e0*2, lp);
        }
        if (tid < 128) sBe[tid] = be[tid];
    }

    // ---- prefetch first E tile (64KB) + A row into registers ----
    const float* Eb = E + (size_t)(b*128 + i0) * 16384;
    f32x4 ebuf[16];
    #pragma unroll
    for (int s = 0; s < 16; ++s)
        ebuf[s] = *(const f32x4*)(Eb + (size_t)(tid + s*256)*4);
    f32x4 abuf = {};
    if (tid < 32) abuf = *(const f32x4*)(A + (size_t)(b*128 + i0)*128 + tid*4);

    __syncthreads();   // WeT + be visible

    float be_r[4];
    #pragma unroll
    for (int n = 0; n < 4; ++n) be_r[n] = sBe[wn + n*16 + (lane & 15)];

    f32x4 P[4][4] = {};   // msg_e partial accumulators (j x f), lives whole loop

    for (int it = 0; it < 8; ++it) {
        // convert & store E tile as hi/lo bf16 (+ A row)
        #pragma unroll
        for (int s = 0; s < 16; ++s) {
            const int flat4 = tid + s*256;
            const int row = flat4 >> 5;          // j
            const int cb  = (flat4 & 31) << 3;   // byte col
            u32x2 hp, lp; split4(ebuf[s], hp, lp);
            stlds8(sEhi, row, cb, hp);
            stlds8(sElo, row, cb, lp);
        }
        if (tid < 32) *(f32x4*)(sA + tid*4) = abuf;
        if (it < 7) {  // register-prefetch next tile: flight during MFMA phase
            const float* En = Eb + (size_t)(it+1)*16384;
            #pragma unroll
            for (int s = 0; s < 16; ++s)
                ebuf[s] = *(const f32x4*)(En + (size_t)(tid + s*256)*4);
            if (tid < 32)
                abuf = *(const f32x4*)(A + (size_t)(b*128 + i0 + it + 1)*128 + tid*4);
        }
        __syncthreads();

        // 128x128x128 GEMM, 3-pass hi/lo
        f32x4 em[4][4] = {};
        #pragma unroll
        for (int k = 0; k < 4; ++k) {
            const int kb = (k << 6) + ((lane >> 4) << 4);
            bf16x8 eh[4], el[4], wh[4], wl[4];
            #pragma unroll
            for (int m = 0; m < 4; ++m) {
                const int row = wm + m*16 + (lane & 15);
                eh[m] = ldfrag(sEhi, row, kb);
                el[m] = ldfrag(sElo, row, kb);
            }
            #pragma unroll
            for (int n = 0; n < 4; ++n) {
                const int row = wn + n*16 + (lane & 15);
                wh[n] = ldfrag(sWhi, row, kb);
                wl[n] = ldfrag(sWlo, row, kb);
            }
            #pragma unroll
            for (int m = 0; m < 4; ++m)
                #pragma unroll
                for (int n = 0; n < 4; ++n) {
                    em[m][n] = MFMA16(eh[m], wh[n], em[m][n]);
                    em[m][n] = MFMA16(eh[m], wl[n], em[m][n]);
                    em[m][n] = MFMA16(el[m], wh[n], em[m][n]);
                }
        }
        // P += A[b,i,j] * relu(em + be)
        #pragma unroll
        for (int m = 0; m < 4; ++m) {
            const f32x4 a4 = *(const f32x4*)(sA + wm + m*16 + ((lane >> 4) << 2));
            #pragma unroll
            for (int n = 0; n < 4; ++n)
                #pragma unroll
                for (int r = 0; r < 4; ++r) {
                    float v = em[m][n][r] + be_r[n];
                    v = fmaxf(v, 0.0f);
                    P[m][n][r] += a4[r] * v;
                }
        }
        __syncthreads();   // all frag reads done before next tile overwrite
    }

    // store partial tile: part[block][j][f]
    float* op = part + (size_t)blockIdx.x * 16384;
    #pragma unroll
    for (int m = 0; m < 4; ++m) {
        const int jb = wm + m*16 + ((lane >> 4) << 2);
        #pragma unroll
        for (int r = 0; r < 4; ++r)
            #pragma unroll
            for (int n = 0; n < 4; ++n)
                op[(jb + r)*128 + wn + n*16 + (lane & 15)] = P[m][n][r];
    }
}

// =====================================================================
// K2: reduce msg_e partials (16 chunks) + compute msg_x = A^T X,
// writing msg[b, j, 0:256]=msg_x, [256:384]=msg_e.  block = (b, 16 j rows)
// =====================================================================
__global__ __launch_bounds__(256) void k_msg(
    const float* __restrict__ A, const float* __restrict__ X,
    const float* __restrict__ part, float* __restrict__ msg)
{
    __shared__ float sAt[128*16];
    const int tid = threadIdx.x;
    const int b   = blockIdx.x >> 3;
    const int jt  = blockIdx.x & 7;
    const int j0  = jt << 4;

    // msg_e: sum 16 chunk partials
    #pragma unroll
    for (int p = 0; p < 8; ++p) {
        const int j = j0 + (tid >> 7) + p*2;
        const int f = tid & 127;
        float s = 0.f;
        #pragma unroll
        for (int cc = 0; cc < 16; ++cc)
            s += part[(size_t)((b*16 + cc)*128 + j)*128 + f];
        msg[(size_t)(b*128 + j)*384 + 256 + f] = s;
    }

    // stage A[b][:, j0:j0+16]
    #pragma unroll
    for (int s = 0; s < 8; ++s) {
        const int i = s*16 + (tid >> 4);
        sAt[i*16 + (tid & 15)] = A[(size_t)(b*128 + i)*128 + j0 + (tid & 15)];
    }
    __syncthreads();

    // msg_x[j, h] = sum_i A[b,i,j] * X[b,i,h];   thread owns column h = tid
    const int h = tid;
    float acc[16];
    #pragma unroll
    for (int jj = 0; jj < 16; ++jj) acc[jj] = 0.f;
    for (int i = 0; i < 128; ++i) {
        const float x = X[(size_t)(b*128 + i)*256 + h];
        #pragma unroll
        for (int jj = 0; jj < 16; ++jj)
            acc[jj] += sAt[i*16 + jj] * x;
    }
    #pragma unroll
    for (int jj = 0; jj < 16; ++jj)
        msg[(size_t)(b*128 + j0 + jj)*384 + h] = acc[jj];
}

// =====================================================================
// K3/K4/K5: tail GEMM  out = [res + ] relu(In @ W + bias)
// In: 2048 x KT row-major, W: KT x 256, out: 2048 x 256.
// 64x64 tile, 4 waves (2x2 of 32x32), Kc=128, hi/lo 3-pass MFMA.
// =====================================================================
template<int KT, bool RES>
__global__ __launch_bounds__(256) void k_tail(
    const float* __restrict__ In, const float* __restrict__ W,
    const float* __restrict__ bias, const float* __restrict__ res,
    const float* __restrict__ epsp, float* __restrict__ out)
{
    __shared__ __align__(16) u16 sAhi[64*128], sAlo[64*128];
    __shared__ __align__(16) u16 sBhi[64*128], sBlo[64*128];   // W^T[n][k]
    const int tid  = threadIdx.x;
    const int lane = tid & 63;
    const int wid  = tid >> 6;
    const int wm   = (wid >> 1) << 5;
    const int wn   = (wid & 1)  << 5;
    const int r0   = blockIdx.x << 6;
    const int h0   = blockIdx.y << 6;

    f32x4 P[2][2] = {};

    for (int k0 = 0; k0 < KT; k0 += 128) {
        #pragma unroll
        for (int s = 0; s < 8; ++s) {           // stage In tile 64x128
            const int row = (tid >> 5) + s*8;
            const int q   = tid & 31;
            f32x4 v = *(const f32x4*)(In + (size_t)(r0 + row)*KT + k0 + q*4);
            u32x2 hp, lp; split4(v, hp, lp);
            stlds8(sAhi, row, q << 3, hp);
            stlds8(sAlo, row, q << 3, lp);
        }
        #pragma unroll
        for (int s = 0; s < 8; ++s) {           // stage W tile transposed
            const int n  = tid & 63;
            const int kq = (tid >> 6) + s*4;    // 0..31
            const int kk = k0 + kq*4;
            f32x4 w;
            w[0] = W[(size_t)(kk+0)*256 + h0 + n];
            w[1] = W[(size_t)(kk+1)*256 + h0 + n];
            w[2] = W[(size_t)(kk+2)*256 + h0 + n];
            w[3] = W[(size_t)(kk+3)*256 + h0 + n];
            u32x2 hp, lp; split4(w, hp, lp);
            stlds8(sBhi, n, kq << 3, hp);
            stlds8(sBlo, n, kq << 3, lp);
        }
        __syncthreads();

        #pragma unroll
        for (int k = 0; k < 4; ++k) {
            const int kb = (k << 6) + ((lane >> 4) << 4);
            bf16x8 ah[2], al[2], bh[2], bl[2];
            #pragma unroll
            for (int m = 0; m < 2; ++m) {
                const int row = wm + m*16 + (lane & 15);
                ah[m] = ldfrag(sAhi, row, kb);
                al[m] = ldfrag(sAlo, row, kb);
            }
            #pragma unroll
            for (int n = 0; n < 2; ++n) {
                const int row = wn + n*16 + (lane & 15);
                bh[n] = ldfrag(sBhi, row, kb);
                bl[n] = ldfrag(sBlo, row, kb);
            }
            #pragma unroll
            for (int m = 0; m < 2; ++m)
                #pragma unroll
                for (int n = 0; n < 2; ++n) {
                    P[m][n] = MFMA16(ah[m], bh[n], P[m][n]);
                    P[m][n] = MFMA16(ah[m], bl[n], P[m][n]);
                    P[m][n] = MFMA16(al[m], bh[n], P[m][n]);
                }
        }
        __syncthreads();
    }

    const float eps = RES ? epsp[0] : 0.f;
    #pragma unroll
    for (int m = 0; m < 2; ++m)
        #pragma unroll
        for (int n = 0; n < 2; ++n) {
            const int hcol = h0 + wn + n*16 + (lane & 15);
            const float bv = bias[hcol];
            #pragma unroll
            for (int e = 0; e < 4; ++e) {
                const int r = r0 + wm + m*16 + ((lane >> 4) << 2) + e;
                float v = fmaxf(P[m][n][e] + bv, 0.f);
                if (RES) v += (1.f + eps) * res[(size_t)r*256 + hcol];
                out[(size_t)r*256 + hcol] = v;
            }
        }
}

extern "C" void kernel_launch(void* const* d_in, const int* in_sizes, int n_in,
                              void* d_out, int out_size, void* d_ws, size_t ws_size,
                              hipStream_t stream)
{
    const float* X   = (const float*)d_in[0];
    const float* E   = (const float*)d_in[1];
    const float* A   = (const float*)d_in[2];
    const float* eps = (const float*)d_in[3];
    const float* We  = (const float*)d_in[4];
    const float* be  = (const float*)d_in[5];
    const float* Wr  = (const float*)d_in[6];
    const float* br  = (const float*)d_in[7];
    const float* W0  = (const float*)d_in[8];
    const float* b0  = (const float*)d_in[9];
    const float* W1  = (const float*)d_in[10];
    const float* b1  = (const float*)d_in[11];
    float* out = (float*)d_out;

    // ws layout (floats): part 16*16*128*128 | msg 2048*384 | out1 | out2  (~23 MB)
    float* part = (float*)d_ws;
    float* msg  = part + 16*16*128*128;
    float* out1 = msg  + 2048*384;
    float* out2 = out1 + 2048*256;

    k_edge<<<256, 256, 0, stream>>>(E, A, We, be, part);
    k_msg <<<128, 256, 0, stream>>>(A, X, part, msg);
    k_tail<384, true ><<<dim3(32,4), 256, 0, stream>>>(msg,  Wr, br, X, eps, out1);
    k_tail<256, false><<<dim3(32,4), 256, 0, stream>>>(out1, W0, b0, nullptr, nullptr, out2);
    k_tail<256, false><<<dim3(32,4), 256, 0, stream>>>(out2, W1, b1, nullptr, nullptr, out);
}